// Round 10
// baseline (1738.797 us; speedup 1.0000x reference)
//
#include <hip/hip_runtime.h>
#include <hip/hip_fp16.h>

typedef float  f4v __attribute__((ext_vector_type(4)));
typedef _Float16 h8v __attribute__((ext_vector_type(8)));
typedef _Float16 h4v __attribute__((ext_vector_type(4)));
typedef unsigned uv4 __attribute__((ext_vector_type(4)));

#define B_ 64
#define T_ 512
#define H_ 1024
#define DELTA_TICKS 180LL   // rendezvous period (100MHz ticks -> 1.8us)
#define HX_DEPTH 4

__global__ __launch_bounds__(256) void k_transpose_cvt(const float* __restrict__ src,
                                                       _Float16* __restrict__ dst) {
  __shared__ _Float16 tile[64][72];
  int r0 = blockIdx.y * 64, c0 = blockIdx.x * 64;
  int t = threadIdx.x;
  for (int i = 0; i < 4; ++i) {
    int r = i * 16 + (t >> 4);
    int c = (t & 15) * 4;
    f4v v = *reinterpret_cast<const f4v*>(src + (long)(r0 + r) * 1024 + c0 + c);
    tile[c + 0][r] = (_Float16)v.x;
    tile[c + 1][r] = (_Float16)v.y;
    tile[c + 2][r] = (_Float16)v.z;
    tile[c + 3][r] = (_Float16)v.w;
  }
  __syncthreads();
  for (int i = 0; i < 2; ++i) {
    int rr = i * 32 + (t >> 3);
    int cc = (t & 7) * 8;
    *reinterpret_cast<h8v*>(dst + (long)(c0 + rr) * 1024 + r0 + cc) =
        *reinterpret_cast<const h8v*>(&tile[rr][cc]);
  }
}

#define SWZG(r, kh) ((((r) * 64) + ((kh) * 2)) ^ (((r) & 3) << 4))

__global__ __launch_bounds__(256) void k_gemm_xu(const float* __restrict__ x,
                                                 const _Float16* __restrict__ Ut,
                                                 const float* __restrict__ bias,
                                                 float* __restrict__ out) {
  __shared__ __attribute__((aligned(16))) unsigned char Asm[128 * 32 * 2];
  __shared__ __attribute__((aligned(16))) unsigned char Bsm[128 * 32 * 2];
  int bid = blockIdx.x;
  int nt = bid & 7, mt = bid >> 3;
  int t = threadIdx.x;
  int row = t >> 1, kc = (t & 1) * 16;
  long gA = (long)(mt * 128 + row) * 1024 + kc;
  long gB = (long)(nt * 128 + row) * 1024 + kc;
  int wid = t >> 6, lane = t & 63;
  int wr = (wid >> 1) * 64, wc = (wid & 1) * 64;
  int l15 = lane & 15, khi = (lane >> 4) * 8;

  f4v acc[4][4];
  for (int i = 0; i < 4; ++i)
    for (int j = 0; j < 4; ++j) acc[i][j] = (f4v){0.f, 0.f, 0.f, 0.f};

  f4v ra[4];
  h8v rb[2];
  {
    const float* ap = x + gA;
    ra[0] = *(const f4v*)(ap);     ra[1] = *(const f4v*)(ap + 4);
    ra[2] = *(const f4v*)(ap + 8); ra[3] = *(const f4v*)(ap + 12);
    const _Float16* bp = Ut + gB;
    rb[0] = *(const h8v*)(bp);     rb[1] = *(const h8v*)(bp + 8);
  }
  for (int kt = 0; kt < 32; ++kt) {
    h8v ah0, ah1;
    for (int j = 0; j < 4; ++j) {
      ah0[j]     = (_Float16)ra[0][j];
      ah0[j + 4] = (_Float16)ra[1][j];
      ah1[j]     = (_Float16)ra[2][j];
      ah1[j + 4] = (_Float16)ra[3][j];
    }
    *(h8v*)(Asm + SWZG(row, kc))     = ah0;
    *(h8v*)(Asm + SWZG(row, kc + 8)) = ah1;
    *(h8v*)(Bsm + SWZG(row, kc))     = rb[0];
    *(h8v*)(Bsm + SWZG(row, kc + 8)) = rb[1];
    __syncthreads();
    if (kt < 31) {
      const float* ap = x + gA + (kt + 1) * 32;
      ra[0] = *(const f4v*)(ap);     ra[1] = *(const f4v*)(ap + 4);
      ra[2] = *(const f4v*)(ap + 8); ra[3] = *(const f4v*)(ap + 12);
      const _Float16* bp = Ut + gB + (kt + 1) * 32;
      rb[0] = *(const h8v*)(bp);     rb[1] = *(const h8v*)(bp + 8);
    }
    h8v af[4], bf[4];
    for (int mi = 0; mi < 4; ++mi)
      af[mi] = *(const h8v*)(Asm + SWZG(wr + mi * 16 + l15, khi));
    for (int ni = 0; ni < 4; ++ni)
      bf[ni] = *(const h8v*)(Bsm + SWZG(wc + ni * 16 + l15, khi));
    for (int mi = 0; mi < 4; ++mi)
      for (int ni = 0; ni < 4; ++ni)
        acc[mi][ni] = __builtin_amdgcn_mfma_f32_16x16x32_f16(af[mi], bf[ni], acc[mi][ni], 0, 0, 0);
    __syncthreads();
  }
  int coff = nt * 128 + wc, roff = mt * 128 + wr;
  for (int ni = 0; ni < 4; ++ni) {
    int col = coff + ni * 16 + l15;
    float bb = bias[col];
    for (int mi = 0; mi < 4; ++mi) {
      int rbase = roff + mi * 16 + (lane >> 4) * 4;
      for (int j = 0; j < 4; ++j)
        out[(long)(rbase + j) * 1024 + col] = acc[mi][ni][j] + bb;
    }
  }
}

// ---------------------------------------------------------------------------
// Persistent scan v10 — clockwork rendezvous.
// Rendezvous by s_memrealtime (device-global clock): tau_s = base + s*DELTA.
// No memory signal on the common-case critical path.  Data = tagged dwords
// (step<<16)|f16 in hx[4][64][1024], sc0sc1 (LLC, refreshing); consumers
// validate tags and retry with backoff -> timing errors cost retries, never
// correctness.  Counter (fire-and-forget bump) feeds (a) early-break if the
// clock is slower than assumed, (b) slot-overwrite guard (depth-4 hx).
// HW model (R2-R9): sc0sc1=LLC refreshing; atomics=MALL, load-polls convoy
// under 31 pollers (the ~2us/step floor this design removes).
// ---------------------------------------------------------------------------
#define SWZS(r, kh) ((((r) * 2048) + ((kh) * 2)) ^ (((r) & 7) << 4))

static __device__ __forceinline__ _Float16 lo_h(unsigned u) {
  unsigned short s = (unsigned short)u;
  _Float16 h;
  __builtin_memcpy(&h, &s, 2);
  return h;
}
static __device__ __forceinline__ unsigned pk(float f, unsigned tg) {
  _Float16 h = (_Float16)f;
  unsigned short s;
  __builtin_memcpy(&s, &h, 2);
  return (tg << 16) | (unsigned)s;
}

__global__ __launch_bounds__(256) void k_scan(const float* __restrict__ state,
                                              float* __restrict__ out,
                                              const _Float16* __restrict__ Wt,
                                              unsigned* __restrict__ hx,
                                              unsigned* __restrict__ ctr) {
  extern __shared__ __attribute__((aligned(16))) unsigned char smem[];
  unsigned char* Wl = smem;          // 32 x 1024 f16, swizzled (64 KB)
  unsigned char* Hl = smem + 65536;  // 8 x 1024 f16 (16 KB)
  __shared__ long long baseS;
  __shared__ int guardok;
  int t = threadIdx.x;
  int bid = blockIdx.x;
  int cl = bid & 7;
  int mm = bid >> 3;
  int lane = t & 63;

  unsigned* stepc = ctr + cl * 32;  // per-cluster progress counter
  unsigned* gbar  = ctr + 512;      // one-time grid barrier

  {  // stage this member's 32 Wt rows into LDS (once)
    int r = t >> 3, c8 = t & 7;
    const _Float16* wsrc = Wt + (long)(mm * 32 + r) * 1024;
    for (int j = 0; j < 16; ++j) {
      int kh = (c8 + 8 * j) * 8;
      *(h8v*)(Wl + SWZS(r, kh)) = *(const h8v*)(wsrc + kh);
    }
  }

  // one-time grid barrier, then a quantized common time base
  if (t == 0) {
    __hip_atomic_fetch_add(gbar, 1u, __ATOMIC_RELAXED, __HIP_MEMORY_SCOPE_AGENT);
    while (__hip_atomic_load(gbar, __ATOMIC_RELAXED, __HIP_MEMORY_SCOPE_AGENT) < 256u)
      __builtin_amdgcn_s_sleep(2);
    unsigned long long rt = __builtin_amdgcn_s_memrealtime();
    baseS = (long long)(((rt >> 8) + 2) << 8);  // round up to 256-tick boundary
    guardok = 1;
  }
  __syncthreads();
  const long long base = baseS;

  int wid = t >> 6;
  int srow = t >> 5, slane = t & 31;
  long b = cl * 8 + srow;
  int l15 = lane & 15, khi8 = (lane >> 4) * 8;
  int arow = lane & 7;
  int bro = wid * 16 + l15;
  int hi = lane >> 4;
  int gcol = mm * 32 + wid * 16 + l15;
  bool prod = (wid < 2) && (hi < 2);

  for (int step = 0; step < T_; ++step) {
    // xu prefetch (own lines) — overlaps the rendezvous wait
    float xuv[4];
    long addr0 = 0;
    if (prod) {
      addr0 = ((long)(cl * 8 + hi * 4) * T_ + step) * 1024 + gcol;
#pragma unroll
      for (int j = 0; j < 4; ++j) xuv[j] = out[addr0 + (long)j * T_ * 1024];
    }

    if (step == 0) {
      const float* hp0 = state + b * 1024 + slane * 4;
#pragma unroll
      for (int j = 0; j < 8; ++j) {
        f4v v = *(const f4v*)(hp0 + 128 * j);
        h4v hv = {(_Float16)v.x, (_Float16)v.y, (_Float16)v.z, (_Float16)v.w};
        *(h4v*)(Hl + SWZS(srow, (slane + 32 * j) * 4)) = hv;
      }
      __syncthreads();
    } else {
      // ---- clockwork rendezvous (t0 spins on the global clock; counter
      // ---- break-early covers a mis-assumed clock rate) ----
      if (t == 0) {
        long long tau = base + (long long)step * DELTA_TICKS;
        unsigned tgt = 32u * (unsigned)step;
        for (;;) {
          long long rt = (long long)__builtin_amdgcn_s_memrealtime();
          if (rt - tau >= 0) break;
          if (__hip_atomic_load(stepc, __ATOMIC_RELAXED, __HIP_MEMORY_SCOPE_AGENT) >= tgt)
            break;
          __builtin_amdgcn_s_sleep(2);
        }
        // slot-overwrite guard (depth-4): all wgs must have bumped step-3
        guardok = 1;
        if (step >= 3) {
          unsigned need = 32u * (unsigned)(step - 2);
          if (__hip_atomic_load(stepc, __ATOMIC_RELAXED, __HIP_MEMORY_SCOPE_AGENT) < need)
            guardok = 0;
        }
      }
      __syncthreads();

      // ---- tagged bulk load of h_{step-1}; tags self-validate, backoff retry
      const unsigned* hp =
          hx + (((step - 1) & (HX_DEPTH - 1)) * 64 + b) * 1024 + slane * 4;
      unsigned tg = (unsigned)(step - 1);
      uv4 c0, c1, c2, c3, c4, c5, c6, c7;
      for (;;) {
        asm volatile(
            "global_load_dwordx4 %0, %8, off sc0 sc1\n\t"
            "global_load_dwordx4 %1, %8, off offset:512 sc0 sc1\n\t"
            "global_load_dwordx4 %2, %8, off offset:1024 sc0 sc1\n\t"
            "global_load_dwordx4 %3, %8, off offset:1536 sc0 sc1\n\t"
            "global_load_dwordx4 %4, %8, off offset:2048 sc0 sc1\n\t"
            "global_load_dwordx4 %5, %8, off offset:2560 sc0 sc1\n\t"
            "global_load_dwordx4 %6, %8, off offset:3072 sc0 sc1\n\t"
            "global_load_dwordx4 %7, %8, off offset:3584 sc0 sc1\n\t"
            "s_waitcnt vmcnt(0)"
            : "=&v"(c0), "=&v"(c1), "=&v"(c2), "=&v"(c3),
              "=&v"(c4), "=&v"(c5), "=&v"(c6), "=&v"(c7)
            : "v"(hp)
            : "memory");
        unsigned d =
            (((c0.x >> 16) ^ tg) | ((c0.y >> 16) ^ tg) | ((c0.z >> 16) ^ tg) | ((c0.w >> 16) ^ tg)) |
            (((c1.x >> 16) ^ tg) | ((c1.y >> 16) ^ tg) | ((c1.z >> 16) ^ tg) | ((c1.w >> 16) ^ tg)) |
            (((c2.x >> 16) ^ tg) | ((c2.y >> 16) ^ tg) | ((c2.z >> 16) ^ tg) | ((c2.w >> 16) ^ tg)) |
            (((c3.x >> 16) ^ tg) | ((c3.y >> 16) ^ tg) | ((c3.z >> 16) ^ tg) | ((c3.w >> 16) ^ tg)) |
            (((c4.x >> 16) ^ tg) | ((c4.y >> 16) ^ tg) | ((c4.z >> 16) ^ tg) | ((c4.w >> 16) ^ tg)) |
            (((c5.x >> 16) ^ tg) | ((c5.y >> 16) ^ tg) | ((c5.z >> 16) ^ tg) | ((c5.w >> 16) ^ tg)) |
            (((c6.x >> 16) ^ tg) | ((c6.y >> 16) ^ tg) | ((c6.z >> 16) ^ tg) | ((c6.w >> 16) ^ tg)) |
            (((c7.x >> 16) ^ tg) | ((c7.y >> 16) ^ tg) | ((c7.z >> 16) ^ tg) | ((c7.w >> 16) ^ tg));
        if (d == 0u) break;
        __builtin_amdgcn_s_sleep(2);
      }
      {
        uv4 cc[8] = {c0, c1, c2, c3, c4, c5, c6, c7};
#pragma unroll
        for (int j = 0; j < 8; ++j) {
          h4v hv = {lo_h(cc[j].x), lo_h(cc[j].y), lo_h(cc[j].z), lo_h(cc[j].w)};
          *(h4v*)(Hl + SWZS(srow, (slane + 32 * j) * 4)) = hv;
        }
      }
      __syncthreads();  // Hl complete (guardok also published)
      if (!guardok) {   // rare: laggard protection before overwriting a slot
        if (t == 0) {
          unsigned need = 32u * (unsigned)(step - 2);
          while (__hip_atomic_load(stepc, __ATOMIC_RELAXED, __HIP_MEMORY_SCOPE_AGENT) < need)
            __builtin_amdgcn_s_sleep(2);
        }
        __syncthreads();
      }
    }

    if (wid < 2) {
      f4v ac0 = (f4v){0.f, 0.f, 0.f, 0.f}, ac1 = ac0, ac2 = ac0, ac3 = ac0;
#pragma unroll
      for (int s = 0; s < 32; s += 4) {
        int k0 = s * 32 + khi8, k1 = k0 + 32, k2 = k0 + 64, k3 = k0 + 96;
        h8v af0 = *(const h8v*)(Hl + SWZS(arow, k0));
        h8v bf0 = *(const h8v*)(Wl + SWZS(bro, k0));
        h8v af1 = *(const h8v*)(Hl + SWZS(arow, k1));
        h8v bf1 = *(const h8v*)(Wl + SWZS(bro, k1));
        h8v af2 = *(const h8v*)(Hl + SWZS(arow, k2));
        h8v bf2 = *(const h8v*)(Wl + SWZS(bro, k2));
        h8v af3 = *(const h8v*)(Hl + SWZS(arow, k3));
        h8v bf3 = *(const h8v*)(Wl + SWZS(bro, k3));
        ac0 = __builtin_amdgcn_mfma_f32_16x16x32_f16(af0, bf0, ac0, 0, 0, 0);
        ac1 = __builtin_amdgcn_mfma_f32_16x16x32_f16(af1, bf1, ac1, 0, 0, 0);
        ac2 = __builtin_amdgcn_mfma_f32_16x16x32_f16(af2, bf2, ac2, 0, 0, 0);
        ac3 = __builtin_amdgcn_mfma_f32_16x16x32_f16(af3, bf3, ac3, 0, 0, 0);
      }
      f4v acc = (ac0 + ac1) + (ac2 + ac3);
      if (hi < 2) {
        float v0 = tanhf(acc[0] + xuv[0]);
        float v1 = tanhf(acc[1] + xuv[1]);
        float v2 = tanhf(acc[2] + xuv[2]);
        float v3 = tanhf(acc[3] + xuv[3]);
        if (step < T_ - 1) {
          unsigned u0 = pk(v0, (unsigned)step), u1 = pk(v1, (unsigned)step);
          unsigned u2 = pk(v2, (unsigned)step), u3 = pk(v3, (unsigned)step);
          unsigned* q0 = hx + ((long)(step & (HX_DEPTH - 1)) * 64 + cl * 8 + hi * 4) * 1024 + gcol;
          unsigned* q1 = q0 + 1024;
          unsigned* q2 = q0 + 2048;
          unsigned* q3 = q0 + 3072;
          asm volatile(
              "global_store_dword %0, %4, off sc0 sc1\n\t"
              "global_store_dword %1, %5, off sc0 sc1\n\t"
              "global_store_dword %2, %6, off sc0 sc1\n\t"
              "global_store_dword %3, %7, off sc0 sc1"
              :: "v"(q0), "v"(q1), "v"(q2), "v"(q3),
                 "v"(u0), "v"(u1), "v"(u2), "v"(u3)
              : "memory");
        }
        out[addr0]                   = v0;
        out[addr0 + (long)T_ * 1024] = v1;
        out[addr0 + (long)T_ * 2048] = v2;
        out[addr0 + (long)T_ * 3072] = v3;
        if (step == T_ - 1) {
          long r = (long)cl * 8 + hi * 4;
          float* q = out + (long)B_ * T_ * 1024 + r * 1024 + gcol;
          q[0] = v0; q[1024] = v1; q[2048] = v2; q[3072] = v3;
        }
      }
    }

    __syncthreads();  // all tagged stores issued wg-wide
    if (t == 0 && step < T_ - 1) {
      __hip_atomic_fetch_add(stepc, 1u, __ATOMIC_RELAXED, __HIP_MEMORY_SCOPE_AGENT);
    }
  }
}

extern "C" void kernel_launch(void* const* d_in, const int* in_sizes, int n_in,
                              void* d_out, int out_size, void* d_ws, size_t ws_size,
                              hipStream_t stream) {
  const float* x     = (const float*)d_in[0];
  const float* state = (const float*)d_in[1];
  const float* W     = (const float*)d_in[2];
  const float* U     = (const float*)d_in[3];
  const float* bias  = (const float*)d_in[4];
  float* out = (float*)d_out;
  unsigned char* ws = (unsigned char*)d_ws;

  _Float16* Ut = (_Float16*)ws;                 // 2 MB (reused as hx after gemm)
  _Float16* Wt = (_Float16*)(ws + (1u << 21));  // 2 MB
  unsigned* hx  = (unsigned*)ws;                // 1 MB (depth 4), aliases Ut
  unsigned* ctr = (unsigned*)(ws + (1u << 22));

  hipMemsetAsync(ctr, 0, 4096, stream);

  k_transpose_cvt<<<dim3(16, 16), 256, 0, stream>>>(U, Ut);
  k_transpose_cvt<<<dim3(16, 16), 256, 0, stream>>>(W, Wt);
  k_gemm_xu<<<2048, 256, 0, stream>>>(x, Ut, bias, out);

  // invalidate hx tags (0xFFFF never matches a step tag); stream-ordered after gemm
  hipMemsetAsync(hx, 0xFF, (size_t)HX_DEPTH * 64u * 1024u * 4u, stream);

  hipFuncSetAttribute((const void*)k_scan, hipFuncAttributeMaxDynamicSharedMemorySize, 81920);
  void* args[] = {(void*)&state, (void*)&out, (void*)&Wt, (void*)&hx, (void*)&ctr};
  hipLaunchCooperativeKernel((void*)k_scan, dim3(256), dim3(256), args, 81920, stream);
}